// Round 8
// baseline (327.520 us; speedup 1.0000x reference)
//
#include <hip/hip_runtime.h>
#include <hip/hip_bf16.h>

// Problem constants (BLoraLinear): T=8192, D_IN=4096, D_OUT=4096, R=16, M=2, S=8
#define T_TOK 8192
#define DIN   4096
#define DOUT  4096
#define RANK  16
#define NMOD  2
#define NSEG  8

typedef __attribute__((ext_vector_type(8))) short bf16x8;
typedef __attribute__((ext_vector_type(8))) unsigned short u16x8;
typedef __attribute__((ext_vector_type(4))) float f32x4;

__device__ inline unsigned short f2bf(float f) {
    union { float f; unsigned u; } v; v.f = f;
    unsigned r = v.u + 0x7FFFu + ((v.u >> 16) & 1u);   // RNE
    return (unsigned short)(r >> 16);
}

__device__ inline void gload_lds16(const void* g, void* l) {
    __builtin_amdgcn_global_load_lds(
        (const __attribute__((address_space(1))) void*)g,
        (__attribute__((address_space(3))) void*)l, 16, 0, 0);
}

// ---------------- fp32 -> bf16 cast for x and W in one launch ----------------
__global__ void cast2_bf16_kernel(const float* __restrict__ sa,
                                  unsigned short* __restrict__ da, int n8a,
                                  const float* __restrict__ sb,
                                  unsigned short* __restrict__ db, int n8b) {
    int i = blockIdx.x * blockDim.x + threadIdx.x;
    const float* s;
    unsigned short* d;
    size_t j;
    if (i < n8a) { s = sa; d = da; j = (size_t)i; }
    else if (i < n8a + n8b) { s = sb; d = db; j = (size_t)(i - n8a); }
    else return;
    const float4* s4 = (const float4*)s;
    float4 a = s4[2 * j];
    float4 b = s4[2 * j + 1];
    u16x8 o;
    o[0] = f2bf(a.x); o[1] = f2bf(a.y); o[2] = f2bf(a.z); o[3] = f2bf(a.w);
    o[4] = f2bf(b.x); o[5] = f2bf(b.y); o[6] = f2bf(b.z); o[7] = f2bf(b.w);
    *(u16x8*)(d + 8 * j) = o;
}

// ---------- At[s][m*16+r][d] = lora_A[m][s][d][r]  (bf16) --------------------
__global__ void prep_A_kernel(const float* __restrict__ A,
                              unsigned short* __restrict__ At) {
    int idx = blockIdx.x * 256 + threadIdx.x;     // NSEG*32*DIN total
    int d   = idx & (DIN - 1);
    int smr = idx >> 12;
    int s   = smr >> 5, mr = smr & 31;
    int m   = mr >> 4,  r  = mr & 15;
    float v = A[(((size_t)(m * NSEG + s) * DIN) + d) * RANK + r];
    At[idx] = f2bf(v);
}

// ---------- Bt[s][o][m*16+r] = lora_B[m][s][r][o]  (bf16) --------------------
__global__ void prep_B_kernel(const float* __restrict__ B,
                              unsigned short* __restrict__ Bt) {
    int o  = blockIdx.x * 256 + threadIdx.x;      // NSEG*DOUT total
    int s  = o >> 12;
    int oc = o & (DOUT - 1);
    unsigned short tmp[32];
    for (int m = 0; m < NMOD; ++m)
        for (int r = 0; r < RANK; ++r)
            tmp[m * 16 + r] =
                f2bf(B[(((size_t)(m * NSEG + s) * RANK) + r) * DOUT + oc]);
    for (int k = 0; k < 4; ++k) {
        u16x8 v;
        for (int j = 0; j < 8; ++j) v[j] = tmp[k * 8 + j];
        *(u16x8*)(Bt + (size_t)o * 32 + k * 8) = v;
    }
}

// ---------- u partials: Pu[ky][t][mr] = sum_{k in split} x[t,k]*At[s(t)][mr][k]
__global__ __launch_bounds__(64) void u_gemm_kernel(
    const unsigned short* __restrict__ xb, const unsigned short* __restrict__ At,
    const int* __restrict__ cu, float* __restrict__ Pu) {
    int tile = blockIdx.x;          // 0..255
    int ky   = blockIdx.y;          // 0..3
    int lane = threadIdx.x;
    int l15  = lane & 15, lk = lane >> 4;
    int t0   = tile * 32;
    f32x4 acc[2][2] = {};
    bf16x8 zero = {};
    for (int s = 0; s < NSEG; ++s) {
        int lo = cu[s], hi = cu[s + 1];
        if (hi <= t0 || lo >= t0 + 32) continue;
        const unsigned short* atb = At + (size_t)(s * 32) * DIN;
        for (int kt = 0; kt < 32; ++kt) {
            int k0 = ky * 1024 + kt * 32 + lk * 8;
            bf16x8 a[2], b[2];
            for (int mi = 0; mi < 2; ++mi) {
                int row = t0 + mi * 16 + l15;
                bf16x8 av = *(const bf16x8*)(xb + (size_t)row * DIN + k0);
                a[mi] = (row >= lo && row < hi) ? av : zero;
            }
            for (int ni = 0; ni < 2; ++ni) {
                int mr = ni * 16 + l15;
                b[ni] = *(const bf16x8*)(atb + (size_t)mr * DIN + k0);
            }
            for (int mi = 0; mi < 2; ++mi)
                for (int ni = 0; ni < 2; ++ni)
                    acc[mi][ni] = __builtin_amdgcn_mfma_f32_16x16x32_bf16(
                        a[mi], b[ni], acc[mi][ni], 0, 0, 0);
        }
    }
    for (int mi = 0; mi < 2; ++mi)
        for (int ni = 0; ni < 2; ++ni)
            for (int j = 0; j < 4; ++j) {
                int t  = t0 + mi * 16 + lk * 4 + j;
                int mr = ni * 16 + l15;
                Pu[((size_t)ky * T_TOK + t) * 32 + mr] = acc[mi][ni][j];
            }
}

// ---------- reduce 4 K-split partials -> ub bf16 [T][32] ---------------------
__global__ void reduce_u_kernel(const float* __restrict__ Pu,
                                unsigned short* __restrict__ ub) {
    int idx = blockIdx.x * 256 + threadIdx.x;   // T_TOK*32
    const size_t STRIDE = (size_t)T_TOK * 32;
    float s = Pu[idx] + Pu[idx + STRIDE] + Pu[idx + 2 * STRIDE] + Pu[idx + 3 * STRIDE];
    ub[idx] = f2bf(s);
}

// ============================================================================
// Main GEMM — read-ahead-one-phase 4-phase schedule. 256x256 tile, BK=64,
// 8 waves (2Mx4N), 2 LDS buffers (128 KiB), 16x16x32 MFMA.
//
// Each phase: [stage gloads] [counted vmcnt: ph0(3)/ph3(2) only] [s_barrier]
//             [ds_reads for NEXT MFMA group] [setprio1; 16 MFMA on PREV
//              group's registers; setprio0] [s_barrier]
// MFMA operands were read one phase (+barrier) earlier -> no lgkm drain before
// the cluster; this phase's reads drain on the LDS pipe WHILE the MFMA pipe
// runs. No lgkmcnt(0), no sched_barrier: compiler emits counted lgkm waits.
//
// A-chunk ROW INTERLEAVE (R6-proven; R7's bug was dropping it):
//   LDS chunk c0 = global rows 0-63, c1 = 128-191, c2 = 64-127, c3 = 192-255.
//   frag rows: mq0 = LDS whalf*64+m*16   -> global whalf*128 + m*16      (acc 0-3)
//              mq1 = LDS 128+whalf*64+.. -> global whalf*128 + 64 + m*16 (acc 4-7)
// Stage plan per K-step t (tile t+1): ph0: B c0,c1,A c0 | ph1: B c2,c3,A c1 |
// ph2: A c2,c3 | ph3: none.
// Read->stage distances: ph3 reads B(t+1) c0-c3 (>=2ph) + A(t+1) c0/c1 (2-3ph);
// ph0 reads A(t) c2/c3 (staged ph2 of t-1, 2ph). vmcnt: ph0 vmcnt(3) leaves
// {B0,B1,A0}; ph3 vmcnt(2) leaves {A2,A3}; both BEFORE the barrier.
// Swizzle (0-conflict, verified R2/R4/R6): byte ^= ((byte>>7)&7)<<4 on 128B
// rows, applied to global SOURCE of global_load_lds (linear dest) and ds_read.
// ============================================================================

__device__ __forceinline__ bf16x8 frag(const char* mat, int row, int kbyte) {
    int rb = (row << 7) + kbyte;
    rb ^= ((rb >> 7) & 7) << 4;
    return *(const bf16x8*)(mat + rb);
}

#define STAGE_B(SB_, C_, K0_)                                                  \
  { int tb = tid * 16;                                                         \
    int lrow = (C_)*64 + (tb >> 7);                                            \
    int cb = (tb & 127) ^ ((lrow & 7) << 4);                                   \
    gload_lds16(wrow_g + (size_t)lrow * DIN + (K0_) + (cb >> 1),               \
                (SB_) + (C_)*8192 + tb); }

// A-chunk with row-block interleave: LDS rows C_*64.. hold global rows GB_+..
#define STAGE_A(SA_, C_, GB_, K0_)                                             \
  { int tb = tid * 16;                                                         \
    int lrow = (C_)*64 + (tb >> 7);                                            \
    int cb = (tb & 127) ^ ((lrow & 7) << 4);                                   \
    gload_lds16(xrow + (size_t)((GB_) + (tb >> 7)) * DIN + (K0_) + (cb >> 1),  \
                (SA_) + (C_)*8192 + tb); }

#define MFMA16(ACCBASE_, AF_, BF_)                                             \
    __builtin_amdgcn_s_setprio(1);                                             \
    for (int m = 0; m < 4; ++m)                                                \
        for (int n = 0; n < 4; ++n)                                            \
            acc[(ACCBASE_) + m][n] = __builtin_amdgcn_mfma_f32_16x16x32_bf16(  \
                AF_[m], BF_[n], acc[(ACCBASE_) + m][n], 0, 0, 0);              \
    __builtin_amdgcn_s_setprio(0);

#define KSTEP(T_, CB_, STG_, LAST_)                                            \
  {                                                                            \
    const char* cA = lds + (CB_)*65536;                                        \
    const char* cB = cA + 32768;                                               \
    char* sA = lds + (1 - (CB_))*65536;                                        \
    char* sB = sA + 32768;                                                     \
    const int k0n = ((T_) + 1) * 64;                                           \
    /* ---- ph0: MFMA G0(afP,bf0); read G1 afQ = A(t,mq1,k0) [LDS c2/c3] ---- */\
    if (STG_) {                                                                \
        STAGE_B(sB, 0, k0n); STAGE_B(sB, 1, k0n); STAGE_A(sA, 0, 0, k0n);      \
        asm volatile("s_waitcnt vmcnt(3)" ::: "memory");                       \
    } else {                                                                   \
        asm volatile("s_waitcnt vmcnt(0)" ::: "memory");                       \
    }                                                                          \
    __builtin_amdgcn_s_barrier();                                              \
    for (int m = 0; m < 4; ++m)                                                \
        afQ[m] = frag(cA, 128 + whalf*64 + m*16 + l15, lk*16);                 \
    MFMA16(0, afP, bf0);                                                       \
    __builtin_amdgcn_s_barrier();                                              \
    /* ---- ph1: MFMA G1(afQ,bf0); read G2 bf1=B(t,k1), afP=A(t,mq0,k1) ---- */\
    if (STG_) { STAGE_B(sB, 2, k0n); STAGE_B(sB, 3, k0n);                      \
                STAGE_A(sA, 1, 128, k0n); }                                    \
    __builtin_amdgcn_s_barrier();                                              \
    for (int n = 0; n < 4; ++n)                                                \
        bf1[n] = frag(cB, wcol + n*16 + l15, 64 + lk*16);                      \
    for (int m = 0; m < 4; ++m)                                                \
        afP[m] = frag(cA, whalf*64 + m*16 + l15, 64 + lk*16);                  \
    MFMA16(4, afQ, bf0);                                                       \
    __builtin_amdgcn_s_barrier();                                              \
    /* ---- ph2: MFMA G2(afP,bf1); read G3 afQ = A(t,mq1,k1) ---- */           \
    if (STG_) { STAGE_A(sA, 2, 64, k0n); STAGE_A(sA, 3, 192, k0n); }           \
    __builtin_amdgcn_s_barrier();                                              \
    for (int m = 0; m < 4; ++m)                                                \
        afQ[m] = frag(cA, 128 + whalf*64 + m*16 + l15, 64 + lk*16);            \
    MFMA16(0, afP, bf1);                                                       \
    __builtin_amdgcn_s_barrier();                                              \
    /* ---- ph3: MFMA G3(afQ,bf1); read next G0 bf0=B(t+1,k0),afP=A(t+1,mq0,k0)*/\
    asm volatile("s_waitcnt vmcnt(2)" ::: "memory");                           \
    __builtin_amdgcn_s_barrier();                                              \
    if (!(LAST_)) {                                                            \
        for (int n = 0; n < 4; ++n)                                            \
            bf0[n] = frag(sB, wcol + n*16 + l15, lk*16);                       \
        for (int m = 0; m < 4; ++m)                                            \
            afP[m] = frag(sA, whalf*64 + m*16 + l15, lk*16);                   \
    }                                                                          \
    MFMA16(4, afQ, bf1);                                                       \
    __builtin_amdgcn_s_barrier();                                              \
  }

__global__ __launch_bounds__(512, 2) void main_gemm_kernel(
    const unsigned short* __restrict__ xb, const unsigned short* __restrict__ wb,
    const unsigned short* __restrict__ ub, const unsigned short* __restrict__ bt,
    const float* __restrict__ bias, const int* __restrict__ cu,
    float* __restrict__ out) {
    __shared__ __attribute__((aligned(1024))) char lds[131072];
    int tid   = threadIdx.x;
    int w     = tid >> 6, lane = tid & 63;
    int l15   = lane & 15, lk = lane >> 4;
    int whalf = w >> 2;                 // wave M-group (0/1)
    int wrow  = whalf * 128;            // wave M-offset in tile
    int wcol  = (w & 3) * 64;           // wave N-offset in tile
    // XCD-aware bijective swizzle: 512 blocks, 8 XCDs, 64 per XCD
    int swz  = (blockIdx.x & 7) * 64 + (blockIdx.x >> 3);
    int row0 = (swz >> 4) * 256;
    int col0 = (swz & 15) * 256;

    const unsigned short* xrow   = xb + (size_t)row0 * DIN;
    const unsigned short* wrow_g = wb + (size_t)col0 * DIN;

    f32x4 acc[8][4] = {};
    bf16x8 bf0[4], bf1[4], afP[4], afQ[4];

    // prologue: stage tile 0 into buffer 0 in steady-state order, then
    // replicate ph3's tail (vmcnt(2); barrier; read G0 of tile 0)
    {
        char* sA = lds;
        char* sB = lds + 32768;
        STAGE_B(sB, 0, 0); STAGE_B(sB, 1, 0); STAGE_A(sA, 0, 0, 0);
        STAGE_B(sB, 2, 0); STAGE_B(sB, 3, 0); STAGE_A(sA, 1, 128, 0);
        STAGE_A(sA, 2, 64, 0); STAGE_A(sA, 3, 192, 0);
    }
    asm volatile("s_waitcnt vmcnt(2)" ::: "memory");
    __builtin_amdgcn_s_barrier();
    for (int n = 0; n < 4; ++n)
        bf0[n] = frag(lds + 32768, wcol + n*16 + l15, lk*16);
    for (int m = 0; m < 4; ++m)
        afP[m] = frag(lds, whalf*64 + m*16 + l15, lk*16);

    // main loop: 64 K-steps of 64
    #pragma unroll 1
    for (int t = 0; t < 62; t += 2) {
        KSTEP(t,     0, 1, 0);
        KSTEP(t + 1, 1, 1, 0);
    }
    KSTEP(62, 0, 1, 0);
    KSTEP(63, 1, 0, 1);

    // fused LoRA up-projection: one extra K=32 MFMA step per overlapping segment
    bf16x8 zero = {};
    for (int s = 0; s < NSEG; ++s) {
        int lo = cu[s], hi = cu[s + 1];
        if (hi <= row0 || lo >= row0 + 256) continue;
        bf16x8 au[8], bu[4];
        for (int m = 0; m < 8; ++m) {
            int row = row0 + wrow + m * 16 + l15;
            bf16x8 v = *(const bf16x8*)(ub + (size_t)row * 32 + lk * 8);
            au[m] = (row >= lo && row < hi) ? v : zero;
        }
        for (int n = 0; n < 4; ++n) {
            int col = col0 + wcol + n * 16 + l15;
            bu[n] = *(const bf16x8*)(bt + ((size_t)s * DOUT + col) * 32 + lk * 8);
        }
        for (int m = 0; m < 8; ++m)
            for (int n = 0; n < 4; ++n)
                acc[m][n] = __builtin_amdgcn_mfma_f32_16x16x32_bf16(
                    au[m], bu[n], acc[m][n], 0, 0, 0);
    }

    // epilogue: + bias, fp32 store
    float bv[4];
    for (int n = 0; n < 4; ++n) bv[n] = bias[col0 + wcol + n * 16 + l15];
    for (int m = 0; m < 8; ++m) {
        int rbase = row0 + wrow + m * 16 + lk * 4;
        for (int n = 0; n < 4; ++n) {
            int col = col0 + wcol + n * 16 + l15;
            for (int jj = 0; jj < 4; ++jj)
                out[(size_t)(rbase + jj) * DOUT + col] = acc[m][n][jj] + bv[n];
        }
    }
}

extern "C" void kernel_launch(void* const* d_in, const int* in_sizes, int n_in,
                              void* d_out, int out_size, void* d_ws, size_t ws_size,
                              hipStream_t stream) {
    const float* x  = (const float*)d_in[0];
    const float* W  = (const float*)d_in[1];
    const float* b  = (const float*)d_in[2];
    const float* lA = (const float*)d_in[3];
    const float* lB = (const float*)d_in[4];
    const int*   cu = (const int*)d_in[5];
    float* out = (float*)d_out;

    char* ws = (char*)d_ws;
    unsigned short* xb = (unsigned short*)(ws);                    // 64 MiB
    unsigned short* wb = (unsigned short*)(ws + 67108864);         // 32 MiB
    unsigned short* At = (unsigned short*)(ws + 100663296);        // 2 MiB
    unsigned short* Bt = (unsigned short*)(ws + 102760448);        // 2 MiB
    float*          Pu = (float*)(ws + 104857600);                 // 4 MiB
    unsigned short* ub = (unsigned short*)(ws + 109051904);        // 0.5 MiB

    const int n8x = T_TOK * DIN / 8, n8w = DOUT * DIN / 8;
    cast2_bf16_kernel<<<(n8x + n8w) / 256, 256, 0, stream>>>(x, xb, n8x, W, wb, n8w);
    prep_A_kernel<<<(NSEG * 32 * DIN) / 256, 256, 0, stream>>>(lA, At);
    prep_B_kernel<<<(NSEG * DOUT) / 256, 256, 0, stream>>>(lB, Bt);
    dim3 ug(T_TOK / 32, 4);
    u_gemm_kernel<<<ug, 64, 0, stream>>>(xb, At, cu, Pu);
    reduce_u_kernel<<<(T_TOK * 32) / 256, 256, 0, stream>>>(Pu, ub);
    dim3 mg(32 * 16);   // 512 tiles of 256x256
    main_gemm_kernel<<<mg, 512, 0, stream>>>(xb, wb, ub, Bt, b, cu, out);
}